// Round 4
// baseline (221.123 us; speedup 1.0000x reference)
//
#include <hip/hip_runtime.h>
#include <math.h>

typedef short bf16x8 __attribute__((ext_vector_type(8)));
typedef short bf16x4 __attribute__((ext_vector_type(4)));
typedef float f32x4  __attribute__((ext_vector_type(4)));

__device__ __forceinline__ unsigned short f2bf(float f) {
    union { float f; unsigned u; } v; v.f = f;
    unsigned r = v.u + 0x7FFFu + ((v.u >> 16) & 1u);   // RNE
    return (unsigned short)(r >> 16);
}

__device__ __forceinline__ unsigned cvt_pk_bf16(float a, float b) {
    unsigned r;
    asm("v_cvt_pk_bf16_f32 %0, %1, %2" : "=v"(r) : "v"(a), "v"(b));
    return r;   // lo16 = bf16(a), hi16 = bf16(b), RNE
}

// async global->LDS, 16B per lane, LDS dest = wave-uniform base + lane*16B
#define GLDS16(gp, lp) __builtin_amdgcn_global_load_lds( \
    (const __attribute__((address_space(1))) void*)(gp), \
    (__attribute__((address_space(3))) void*)(lp), 16, 0, 0)

// Head-dim permutation: MFMA-C position (nt*16+c) stored at byte position
// (c*4+nt) within each 64-wide head block. Q,K share pi (dot invariant);
// V/Ab use sigma; Wto compensates. Q additionally pre-scaled by 0.125.

// ---------------------------------------------------------------------------
// prep: z<4 -> W fp32 [k][n] -> Wt bf16 [n][k] (z=3 un-permutes sigma(pi));
//       z>=4 -> X fp32 -> bf16 copy-convert
// ---------------------------------------------------------------------------
__global__ __launch_bounds__(256)
void prep(const float* __restrict__ X, unsigned short* __restrict__ Xb,
          const float* __restrict__ w0, const float* __restrict__ w1,
          const float* __restrict__ w2, const float* __restrict__ w3,
          unsigned short* o0, unsigned short* o1,
          unsigned short* o2, unsigned short* o3)
{
    const int z = blockIdx.z;
    if (z >= 4) {
        const int lb = (z - 4) * 256 + blockIdx.y * 16 + blockIdx.x;
        const size_t t = (size_t)lb * 256 + threadIdx.x;
        const float4 a = *(const float4*)(X + t * 8);
        const float4 b = *(const float4*)(X + t * 8 + 4);
        unsigned short u[8] = { f2bf(a.x), f2bf(a.y), f2bf(a.z), f2bf(a.w),
                                f2bf(b.x), f2bf(b.y), f2bf(b.z), f2bf(b.w) };
        *(int4*)(Xb + t * 8) = *(int4*)u;
        return;
    }
    const float* W; unsigned short* O;
    switch (z) {
        case 0: W = w0; O = o0; break;
        case 1: W = w1; O = o1; break;
        case 2: W = w2; O = o2; break;
        default: W = w3; O = o3; break;
    }
    __shared__ float T[64][65];
    const int tid = threadIdx.x;
    const int n0 = blockIdx.x * 64, k0 = blockIdx.y * 64;
    #pragma unroll
    for (int i = 0; i < 4; i++) {
        const int k = (tid >> 4) + i * 16, n4 = (tid & 15) * 4;
        const float4 v = *(const float4*)(W + (size_t)(k0 + k) * 1024 + n0 + n4);
        T[k][n4] = v.x; T[k][n4+1] = v.y; T[k][n4+2] = v.z; T[k][n4+3] = v.w;
    }
    __syncthreads();
    if (z == 3) {
        #pragma unroll
        for (int i = 0; i < 4; i++) {
            const int n = (tid >> 4) + i * 16, k4 = (tid & 15) * 4;
            unsigned short u[4];
            #pragma unroll
            for (int j = 0; j < 4; j++) {
                const int q = k4 + j;                      // Ab storage pos
                const int p = (q & 3) * 16 + (q >> 2);     // inv sigma
                const int d = (p & 3) * 16 + (p >> 2);     // inv pi
                u[j] = f2bf(T[d][n]);
            }
            *(int2*)(O + (size_t)(n0 + n) * 1024 + k0 + k4) = *(int2*)u;
        }
    } else {
        #pragma unroll
        for (int i = 0; i < 4; i++) {
            const int n = (tid >> 4) + i * 16, k4 = (tid & 15) * 4;
            unsigned short u[4] = { f2bf(T[k4][n]), f2bf(T[k4+1][n]),
                                    f2bf(T[k4+2][n]), f2bf(T[k4+3][n]) };
            *(int2*)(O + (size_t)(n0 + n) * 1024 + k0 + k4) = *(int2*)u;
        }
    }
}

// ---------------------------------------------------------------------------
// QKV GEMM, R14: tile 128x64, grid (32,16,3) = 1536 blocks = 6/CU (was 3).
// Rationale: kernel is latency-bound on the vmcnt(0) barrier drain; more
// co-resident blocks = more independent K-loop streams per CU. Wave = 32
// rows x 64 cols (acc[2][4]); each 64-wide tile is exactly one head, so
// RoPE pairing and the sigma pack stay wave-local. V epilogue is single-
// phase (one head per tile).
// ---------------------------------------------------------------------------
__global__ __launch_bounds__(256)
void qkv_gemm(const unsigned short* __restrict__ Xb,
              const unsigned short* __restrict__ Wtq, const unsigned short* __restrict__ Wtk,
              const unsigned short* __restrict__ Wtv,
              const float* __restrict__ bq, const float* __restrict__ bk,
              const float* __restrict__ bv,
              unsigned short* __restrict__ Qb, unsigned short* __restrict__ Kb,
              unsigned short* __restrict__ Vtb)
{
    const unsigned short* Wt; const float* bias; unsigned short* Out;
    const int z = blockIdx.z;
    if (z == 0)      { Wt = Wtq; bias = bq; Out = Qb; }
    else if (z == 1) { Wt = Wtk; bias = bk; Out = Kb; }
    else             { Wt = Wtv; bias = bv; Out = Vtb; }

    __shared__ unsigned short Sh[128 * 72];          // 18.4 KB (T needs it)
    unsigned short* As = Sh;                         // 128*32 staging [m][k]
    unsigned short* Bs = Sh + 128 * 32;              // 64*32 staging [n][k]
    unsigned short* T  = Sh;                         // 128*72 epilogue transpose

    const int tid = threadIdx.x, lane = tid & 63, w = tid >> 6;
    const int quad = lane >> 4, c = lane & 15;
    const int m0 = blockIdx.x * 128, n0 = blockIdx.y * 64;
    const int srow = lane >> 2, scol = (lane & 3) * 8;

    f32x4 acc[2][4];
    #pragma unroll
    for (int i = 0; i < 2; i++)
        #pragma unroll
        for (int j = 0; j < 4; j++) acc[i][j] = (f32x4){0.f, 0.f, 0.f, 0.f};

    for (int k0 = 0; k0 < 1024; k0 += 32) {
        #pragma unroll
        for (int j = 0; j < 2; j++) {
            const int r = w * 32 + j * 16;
            GLDS16(Xb + (size_t)(m0 + r + srow) * 1024 + k0 + scol, &As[r * 32]);
        }
        {
            const int r = w * 16;
            GLDS16(Wt + (size_t)(n0 + r + srow) * 1024 + k0 + scol, &Bs[r * 32]);
        }
        __syncthreads();
        bf16x8 af[2], bf[4];
        #pragma unroll
        for (int rt = 0; rt < 2; rt++)
            af[rt] = *(const bf16x8*)&As[(w * 32 + rt * 16 + c) * 32 + quad * 8];
        #pragma unroll
        for (int nt = 0; nt < 4; nt++)
            bf[nt] = *(const bf16x8*)&Bs[(nt * 16 + c) * 32 + quad * 8];
        #pragma unroll
        for (int rt = 0; rt < 2; rt++)
            #pragma unroll
            for (int nt = 0; nt < 4; nt++)
                acc[rt][nt] = __builtin_amdgcn_mfma_f32_16x16x32_bf16(af[rt], bf[nt], acc[rt][nt], 0, 0, 0);
        __syncthreads();
    }

    float bv4[4];
    #pragma unroll
    for (int nt = 0; nt < 4; nt++) bv4[nt] = bias[n0 + nt * 16 + c];

    if (z == 2) {
        const int b = m0 >> 11, sb = m0 & 2047;
        const int hg = n0 >> 6;
        #pragma unroll
        for (int rt = 0; rt < 2; rt++)
            #pragma unroll
            for (int reg = 0; reg < 4; reg++) {
                const int s = w * 32 + rt * 16 + quad * 4 + reg;   // [0,128)
                unsigned short u[4];
                #pragma unroll
                for (int nt = 0; nt < 4; nt++)
                    u[nt] = f2bf(acc[rt][nt][reg] + bv4[nt]);
                *(int2*)&T[s * 72 + c * 4] = *(int2*)u;   // p = c*4+nt (sigma)
            }
        __syncthreads();
        const int p = tid >> 2, s8 = (tid & 3) * 32;
        unsigned short* dstb = Vtb + ((size_t)(b * 16 + hg) * 64 + p) * 2048 + sb;
        #pragma unroll
        for (int jj = 0; jj < 32; jj += 8) {
            unsigned short u[8];
            #pragma unroll
            for (int j = 0; j < 8; j++) u[j] = T[(s8 + jj + j) * 72 + p];
            *(int4*)(dstb + s8 + jj) = *(int4*)u;
        }
        return;
    }

    const float kLn = 9.210340371976184f / 32.0f;   // ln(10000)/32
    const float TWO_PI_INV = 0.15915494309189535f;
    const float rv0 = expf(-(float)c * kLn) * TWO_PI_INV;
    const float rv1 = expf(-(float)(c + 16) * kLn) * TWO_PI_INV;
    const float qscale = (z == 0) ? 0.125f : 1.0f;  // fold 1/sqrt(64) into Q
    const int h = n0 >> 6;

    #pragma unroll
    for (int rt = 0; rt < 2; rt++) {
        #pragma unroll
        for (int reg = 0; reg < 4; reg++) {
            const int m = m0 + w * 32 + rt * 16 + quad * 4 + reg;
            const int b = m >> 11, s = m & 2047;
            float x0 = acc[rt][0][reg] + bv4[0];
            float x1 = acc[rt][1][reg] + bv4[1];
            float x2 = acc[rt][2][reg] + bv4[2];
            float x3 = acc[rt][3][reg] + bv4[3];
            float r0 = (float)s * rv0;  r0 -= floorf(r0);
            float r1 = (float)s * rv1;  r1 -= floorf(r1);
            const float sn0 = __builtin_amdgcn_sinf(r0);
            const float cs0 = __builtin_amdgcn_cosf(r0);
            const float sn1 = __builtin_amdgcn_sinf(r1);
            const float cs1 = __builtin_amdgcn_cosf(r1);
            const float y0 = (x0 * cs0 - x2 * sn0) * qscale;
            const float y2 = (x0 * sn0 + x2 * cs0) * qscale;
            const float y1 = (x1 * cs1 - x3 * sn1) * qscale;
            const float y3 = (x1 * sn1 + x3 * cs1) * qscale;
            unsigned short u[4] = { f2bf(y0), f2bf(y1), f2bf(y2), f2bf(y3) };
            unsigned short* dst = Out + ((size_t)(b * 16 + h) * 2048 + s) * 64;
            *(int2*)(dst + c * 4) = *(int2*)u;     // pi: pos c*4+nt
        }
    }
}

// ---------------------------------------------------------------------------
// Output projection GEMM (unchanged): 64x128 tile, 512 blocks (2/CU).
// ---------------------------------------------------------------------------
__global__ __launch_bounds__(256)
void out_gemm(const unsigned short* __restrict__ Ab, const unsigned short* __restrict__ Wto,
              const float* __restrict__ bo, float* __restrict__ Out)
{
    __shared__ unsigned short As[64 * 32];
    __shared__ unsigned short Bs[128 * 32];
    const int tid = threadIdx.x, lane = tid & 63, w = tid >> 6;
    const int quad = lane >> 4, c = lane & 15;
    const int wr = w >> 1, wc = w & 1;
    const int m0 = blockIdx.x * 64, n0 = blockIdx.y * 128;
    const int srow = lane >> 2, scol = (lane & 3) * 8;

    f32x4 acc[2][4];
    #pragma unroll
    for (int i = 0; i < 2; i++)
        #pragma unroll
        for (int j = 0; j < 4; j++) acc[i][j] = (f32x4){0.f, 0.f, 0.f, 0.f};

    for (int k0 = 0; k0 < 1024; k0 += 32) {
        {
            const int r = w * 16;
            GLDS16(Ab + (size_t)(m0 + r + srow) * 1024 + k0 + scol, &As[r * 32]);
        }
        #pragma unroll
        for (int j = 0; j < 2; j++) {
            const int r = w * 32 + j * 16;
            GLDS16(Wto + (size_t)(n0 + r + srow) * 1024 + k0 + scol, &Bs[r * 32]);
        }
        __syncthreads();
        bf16x8 af[2], bf[4];
        #pragma unroll
        for (int rt = 0; rt < 2; rt++)
            af[rt] = *(const bf16x8*)&As[(wr * 32 + rt * 16 + c) * 32 + quad * 8];
        #pragma unroll
        for (int nt = 0; nt < 4; nt++)
            bf[nt] = *(const bf16x8*)&Bs[(wc * 64 + nt * 16 + c) * 32 + quad * 8];
        #pragma unroll
        for (int rt = 0; rt < 2; rt++)
            #pragma unroll
            for (int nt = 0; nt < 4; nt++)
                acc[rt][nt] = __builtin_amdgcn_mfma_f32_16x16x32_bf16(af[rt], bf[nt], acc[rt][nt], 0, 0, 0);
        __syncthreads();
    }
    #pragma unroll
    for (int rt = 0; rt < 2; rt++) {
        #pragma unroll
        for (int reg = 0; reg < 4; reg++) {
            const int m = m0 + wr * 32 + rt * 16 + quad * 4 + reg;
            #pragma unroll
            for (int nt = 0; nt < 4; nt++) {
                const int n = n0 + wc * 64 + nt * 16 + c;
                Out[(size_t)m * 1024 + n] = acc[rt][nt][reg] + bo[n];
            }
        }
    }
}

// ---------------------------------------------------------------------------
// Split-K flash attention (unchanged from R13): 512 threads, 8 waves,
// 32 q/wave via 2 Q-fragments, P fully in-register (kappa relabel).
// ---------------------------------------------------------------------------
__global__ __launch_bounds__(512)
void attn_part(const unsigned short* __restrict__ Qb, const unsigned short* __restrict__ Kb,
               const unsigned short* __restrict__ Vtb, unsigned short* __restrict__ Ab,
               float* __restrict__ Opart, float* __restrict__ Lpart)
{
    __shared__ unsigned short Ks[64 * 72];      // [key][d], pitch 144B
    __shared__ unsigned short Vs[64 * 72];      // [p][key], pitch 144B

    const int tid = threadIdx.x, w = tid >> 6, lane = tid & 63;
    const int quad = lane >> 4, c = lane & 15;
    const int bh = blockIdx.y;
    const int x = blockIdx.x;
    // i per x: {7,7,3,6,6,5,5,2,4,4,1,0}; chunk1 at x in {1,4,6,9}
    const int i = (int)((0x014425566377ULL >> (4 * x)) & 15);
    const int chunk = (594 >> x) & 1;                   // bits 1,4,6,9
    const int len = ((i >= 4) ? 2 : 4) * (i + 1);
    const int start = chunk ? len : 0;
    const int q0 = i * 256;
    const bool complete = (i <= 3);
    const size_t base = (size_t)bh * 2048 * 64;

    bf16x8 on;                                  // bf16 1.0 x8 (ones column)
    #pragma unroll
    for (int ii = 0; ii < 8; ii++) on[ii] = (short)0x3F80;

    const int qbase = q0 + w * 32;              // wave owns rows [qbase, qbase+32)
    const size_t qoffA = base + (size_t)(qbase + c) * 64;
    const size_t qoffB = base + (size_t)(qbase + 16 + c) * 64;
    const bf16x8 qfA0 = *(const bf16x8*)(Qb + qoffA + quad * 8);
    const bf16x8 qfA1 = *(const bf16x8*)(Qb + qoffA + 32 + quad * 8);
    const bf16x8 qfB0 = *(const bf16x8*)(Qb + qoffB + quad * 8);
    const bf16x8 qfB1 = *(const bf16x8*)(Qb + qoffB + 32 + quad * 8);

    f32x4 OA[4], OB[4], OsA, OsB;
    OsA = (f32x4){0.f, 0.f, 0.f, 0.f};
    OsB = (f32x4){0.f, 0.f, 0.f, 0.f};
    #pragma unroll
    for (int nt = 0; nt < 4; nt++) { OA[nt] = OsA; OB[nt] = OsA; }

    // staging: 512 threads cover 64 rows x 64 elems (16B each) in one shot
    const int rs = tid >> 3, c8 = (tid & 7) * 8;

    int k0 = start * 64;
    int4 kreg = *(const int4*)(Kb  + base + (size_t)(k0 + rs) * 64 + c8);
    int4 vreg = *(const int4*)(Vtb + base + (size_t)rs * 2048 + k0 + c8);

    union P8 { bf16x8 v8; unsigned wd[4]; };
    union V8 { bf16x8 v8; bf16x4 v4[2]; };

    for (int t = 0; t < len; t++, k0 += 64) {
        *(int4*)&Ks[(size_t)rs * 72 + c8] = kreg;
        *(int4*)&Vs[(size_t)rs * 72 + c8] = vreg;
        __syncthreads();

        if (t + 1 < len) {
            const int kn = k0 + 64;
            kreg = *(const int4*)(Kb  + base + (size_t)(kn + rs) * 64 + c8);
            vreg = *(const int4*)(Vtb + base + (size_t)rs * 2048 + kn + c8);
        }

        if (k0 <= qbase + 31) {                 // wave-uniform: else fully masked
            const int qrowA = qbase + c;
            const int qrowB = qbase + 16 + c;
            const bool nmA = (k0 + 63) > qbase;
            const bool nmB = (k0 + 63) > (qbase + 16);
            P8 paA0, paA1, paB0, paB1;
            __builtin_amdgcn_s_setprio(1);
            #pragma unroll
            for (int nt = 0; nt < 4; nt++) {
                const bf16x8 kf0 = *(const bf16x8*)&Ks[(nt * 16 + c) * 72 + quad * 8];
                const bf16x8 kf1 = *(const bf16x8*)&Ks[(nt * 16 + c) * 72 + 32 + quad * 8];
                f32x4 sA = (f32x4){0.f, 0.f, 0.f, 0.f};
                f32x4 sB = sA;
                sA = __builtin_amdgcn_mfma_f32_16x16x32_bf16(kf0, qfA0, sA, 0, 0, 0);
                sA = __builtin_amdgcn_mfma_f32_16x16x32_bf16(kf1, qfA1, sA, 0, 0, 0);
                sB = __builtin_amdgcn_mfma_f32_16x16x32_bf16(kf0, qfB0, sB, 0, 0, 0);
                sB = __builtin_amdgcn_mfma_f32_16x16x32_bf16(kf1, qfB1, sB, 0, 0, 0);
                const int keyb = k0 + nt * 16 + quad * 4;
                float pA[4], pB[4];
                #pragma unroll
                for (int reg = 0; reg < 4; reg++) {
                    float va = __expf(sA[reg]);           // Q pre-scaled by 0.125
                    if (nmA && (keyb + reg > qrowA)) va = 0.f;
                    pA[reg] = va;
                    float vb = __expf(sB[reg]);
                    if (nmB && (keyb + reg > qrowB)) vb = 0.f;
                    pB[reg] = vb;
                }
                const unsigned waA = cvt_pk_bf16(pA[0], pA[1]);
                const unsigned wbA = cvt_pk_bf16(pA[2], pA[3]);
                const unsigned waB = cvt_pk_bf16(pB[0], pB[1]);
                const unsigned wbB = cvt_pk_bf16(pB[2], pB[3]);
                // kappa mapping: frag (nt>>1), words 2*(nt&1)+{0,1}
                if (nt < 2) {
                    paA0.wd[2 * nt] = waA;     paA0.wd[2 * nt + 1] = wbA;
                    paB0.wd[2 * nt] = waB;     paB0.wd[2 * nt + 1] = wbB;
                } else {
                    paA1.wd[2 * (nt-2)] = waA; paA1.wd[2 * (nt-2) + 1] = wbA;
                    paB1.wd[2 * (nt-2)] = waB; paB1.wd[2 * (nt-2) + 1] = wbB;
                }
            }

            // ---- PV + row-sum; vb reads shared by both fragments ----
            #pragma unroll
            for (int nt = 0; nt < 4; nt++) {
                const int pr = (nt * 16 + c) * 72 + 4 * quad;
                V8 vb0, vb1;
                vb0.v4[0] = *(const bf16x4*)&Vs[pr];
                vb0.v4[1] = *(const bf16x4*)&Vs[pr + 16];
                vb1.v4[0] = *(const bf16x4*)&Vs[pr + 32];
                vb1.v4[1] = *(const bf16x4*)&Vs[pr + 48];
                OA[nt] = __builtin_amdgcn_mfma_f32_16x16x32_bf16(paA0.v8, vb0.v8, OA[nt], 0, 0, 0);
                OA[nt] = __builtin_amdgcn_mfma_f32_16x16x32_bf16(paA1.v8, vb1.v8, OA[nt], 0, 0, 0);
                OB[nt] = __builtin_amdgcn_mfma_f32_16x16x32_bf16(paB0.v8, vb0.v8, OB[nt], 0, 0, 0);
                OB[nt] = __builtin_amdgcn_mfma_f32_16x16x32_bf16(paB1.v8, vb1.v8, OB[nt], 0, 0, 0);
            }
            OsA = __builtin_amdgcn_mfma_f32_16x16x32_bf16(paA0.v8, on, OsA, 0, 0, 0);
            OsA = __builtin_amdgcn_mfma_f32_16x16x32_bf16(paA1.v8, on, OsA, 0, 0, 0);
            OsB = __builtin_amdgcn_mfma_f32_16x16x32_bf16(paB0.v8, on, OsB, 0, 0, 0);
            OsB = __builtin_amdgcn_mfma_f32_16x16x32_bf16(paB1.v8, on, OsB, 0, 0, 0);
            __builtin_amdgcn_s_setprio(0);
        }
        __syncthreads();
    }

    if (complete) {
        const int b = bh >> 4, h = bh & 15;
        #pragma unroll
        for (int reg = 0; reg < 4; reg++) {
            const float invA = 1.0f / OsA[reg];
            const int qA = qbase + quad * 4 + reg;
            unsigned short uA[4];
            #pragma unroll
            for (int nt = 0; nt < 4; nt++) uA[nt] = f2bf(OA[nt][reg] * invA);
            unsigned short* dA = Ab + ((size_t)(b * 2048 + qA)) * 1024 + h * 64;
            *(int2*)(dA + c * 4) = *(int2*)uA;     // sigma: pos c*4+nt

            const float invB = 1.0f / OsB[reg];
            const int qB = qbase + 16 + quad * 4 + reg;
            unsigned short uB[4];
            #pragma unroll
            for (int nt = 0; nt < 4; nt++) uB[nt] = f2bf(OB[nt][reg] * invB);
            unsigned short* dB = Ab + ((size_t)(b * 2048 + qB)) * 1024 + h * 64;
            *(int2*)(dB + c * 4) = *(int2*)uB;
        }
    } else {
        const int slot = (i - 4) * 2 + chunk;               // [0,8)
        float* Op = Opart + ((size_t)bh * 8 + slot) * 16384;
        float* Lp = Lpart + (size_t)bh * 2048 + (size_t)slot * 256;
        #pragma unroll
        for (int reg = 0; reg < 4; reg++) {
            const int rowA = w * 32 + quad * 4 + reg;       // [0,256)
            float4 oA = make_float4(OA[0][reg], OA[1][reg], OA[2][reg], OA[3][reg]);
            *(float4*)(Op + (size_t)rowA * 64 + c * 4) = oA;  // sigma order
            if (c == 0) Lp[rowA] = OsA[reg];

            const int rowB = rowA + 16;
            float4 oB = make_float4(OB[0][reg], OB[1][reg], OB[2][reg], OB[3][reg]);
            *(float4*)(Op + (size_t)rowB * 64 + c * 4) = oB;
            if (c == 0) Lp[rowB] = OsB[reg];
        }
    }
}

// ---------------------------------------------------------------------------
// Combine two partials per (bh, q-tile256 i=4..7): O=O0+O1, normalize, bf16.
// grid (8,32): j -> (i = 4 + j/2, half = j&1) covering 128 rows each.
// ---------------------------------------------------------------------------
__global__ __launch_bounds__(256)
void attn_combine(const float* __restrict__ Opart, const float* __restrict__ Lpart,
                  unsigned short* __restrict__ Ab)
{
    const int tid = threadIdx.x;
    const int j = blockIdx.x, bh = blockIdx.y;
    const int i = 4 + (j >> 1), half = j & 1;
    const int slot0 = (i - 4) * 2;
    const int q0 = i * 256 + half * 128;
    const size_t s0 = ((size_t)bh * 8 + slot0) * 16384 + (size_t)half * 128 * 64;
    const size_t l0 = (size_t)bh * 2048 + (size_t)slot0 * 256 + half * 128;

    __shared__ float linv[128];
    if (tid < 128) linv[tid] = 1.0f / (Lpart[l0 + tid] + Lpart[l0 + 256 + tid]);
    __syncthreads();

    const int row = tid >> 1, col0 = (tid & 1) * 32;
    const float inv = linv[row];
    const int b = bh >> 4, h = bh & 15;
    const int q = q0 + row;
    unsigned short* dst = Ab + ((size_t)(b * 2048 + q)) * 1024 + h * 64 + col0;
    #pragma unroll
    for (int c4 = 0; c4 < 32; c4 += 4) {
        const float4 a  = *(const float4*)(Opart + s0 + (size_t)row * 64 + col0 + c4);
        const float4 bb = *(const float4*)(Opart + s0 + 16384 + (size_t)row * 64 + col0 + c4);
        dst[c4 + 0] = f2bf((a.x + bb.x) * inv);
        dst[c4 + 1] = f2bf((a.y + bb.y) * inv);
        dst[c4 + 2] = f2bf((a.z + bb.z) * inv);
        dst[c4 + 3] = f2bf((a.w + bb.w) * inv);
    }
}

// ---------------------------------------------------------------------------
extern "C" void kernel_launch(void* const* d_in, const int* in_sizes, int n_in,
                              void* d_out, int out_size, void* d_ws, size_t ws_size,
                              hipStream_t stream)
{
    const float* X  = (const float*)d_in[0];
    const float* wq = (const float*)d_in[2];
    const float* bq = (const float*)d_in[3];
    const float* wk = (const float*)d_in[4];
    const float* bk = (const float*)d_in[5];
    const float* wv = (const float*)d_in[6];
    const float* bv = (const float*)d_in[7];
    const float* wo = (const float*)d_in[8];
    const float* bo = (const float*)d_in[9];

    unsigned short* ws = (unsigned short*)d_ws;
    const size_t M1 = 1024 * 1024;
    unsigned short* Xb  = ws;             // 4M elems
    unsigned short* Wtq = Xb  + 4 * M1;   // 1M each
    unsigned short* Wtk = Wtq + M1;
    unsigned short* Wtv = Wtk + M1;
    unsigned short* Wto = Wtv + M1;
    unsigned short* Qb  = Wto + M1;       // 4M each
    unsigned short* Kb  = Qb  + 4 * M1;
    unsigned short* Vtb = Kb  + 4 * M1;   // V^T written directly by qkv_gemm
    unsigned short* Ab  = Vtb + 4 * M1;   // bf16, 4M elems
    float* Opart = (float*)(Ab + 4 * M1); // 32*8*16384 fp32 = 16 MB
    float* Lpart = Opart + (size_t)32 * 8 * 16384;  // 64K fp32

    prep        <<<dim3(16, 16, 12), 256, 0, stream>>>(X, Xb, wq, wk, wv, wo,
                                                       Wtq, Wtk, Wtv, Wto);
    qkv_gemm    <<<dim3(32, 16, 3), 256, 0, stream>>>(Xb, Wtq, Wtk, Wtv, bq, bk, bv,
                                                      Qb, Kb, Vtb);
    attn_part   <<<dim3(12, 32), 512, 0, stream>>>(Qb, Kb, Vtb, Ab, Opart, Lpart);
    attn_combine<<<dim3(8, 32), 256, 0, stream>>>(Opart, Lpart, Ab);
    out_gemm    <<<dim3(64, 8), 256, 0, stream>>>(Ab, Wto, bo, (float*)d_out);
}

// Round 6
// 212.690 us; speedup vs baseline: 1.0397x; 1.0397x over previous
//
#include <hip/hip_runtime.h>
#include <math.h>

typedef short bf16x8 __attribute__((ext_vector_type(8)));
typedef short bf16x4 __attribute__((ext_vector_type(4)));
typedef float f32x4  __attribute__((ext_vector_type(4)));

__device__ __forceinline__ unsigned short f2bf(float f) {
    union { float f; unsigned u; } v; v.f = f;
    unsigned r = v.u + 0x7FFFu + ((v.u >> 16) & 1u);   // RNE
    return (unsigned short)(r >> 16);
}

__device__ __forceinline__ unsigned cvt_pk_bf16(float a, float b) {
    unsigned r;
    asm("v_cvt_pk_bf16_f32 %0, %1, %2" : "=v"(r) : "v"(a), "v"(b));
    return r;   // lo16 = bf16(a), hi16 = bf16(b), RNE
}

// async global->LDS, 16B per lane, LDS dest = wave-uniform base + lane*16B
#define GLDS16(gp, lp) __builtin_amdgcn_global_load_lds( \
    (const __attribute__((address_space(1))) void*)(gp), \
    (__attribute__((address_space(3))) void*)(lp), 16, 0, 0)

// Head-dim permutation: MFMA-C position (nt*16+c) stored at byte position
// (c*4+nt) within each 64-wide head block. Q,K share pi (dot invariant);
// V/Ab use sigma; Wto compensates. Q additionally pre-scaled by 0.125.

// ---------------------------------------------------------------------------
// prep: z<4 -> W fp32 [k][n] -> Wt bf16 [n][k] (z=3 un-permutes sigma(pi));
//       z>=4 -> X fp32 -> bf16 copy-convert
// ---------------------------------------------------------------------------
__global__ __launch_bounds__(256)
void prep(const float* __restrict__ X, unsigned short* __restrict__ Xb,
          const float* __restrict__ w0, const float* __restrict__ w1,
          const float* __restrict__ w2, const float* __restrict__ w3,
          unsigned short* o0, unsigned short* o1,
          unsigned short* o2, unsigned short* o3)
{
    const int z = blockIdx.z;
    if (z >= 4) {
        const int lb = (z - 4) * 256 + blockIdx.y * 16 + blockIdx.x;
        const size_t t = (size_t)lb * 256 + threadIdx.x;
        const float4 a = *(const float4*)(X + t * 8);
        const float4 b = *(const float4*)(X + t * 8 + 4);
        unsigned short u[8] = { f2bf(a.x), f2bf(a.y), f2bf(a.z), f2bf(a.w),
                                f2bf(b.x), f2bf(b.y), f2bf(b.z), f2bf(b.w) };
        *(int4*)(Xb + t * 8) = *(int4*)u;
        return;
    }
    const float* W; unsigned short* O;
    switch (z) {
        case 0: W = w0; O = o0; break;
        case 1: W = w1; O = o1; break;
        case 2: W = w2; O = o2; break;
        default: W = w3; O = o3; break;
    }
    __shared__ float T[64][65];
    const int tid = threadIdx.x;
    const int n0 = blockIdx.x * 64, k0 = blockIdx.y * 64;
    #pragma unroll
    for (int i = 0; i < 4; i++) {
        const int k = (tid >> 4) + i * 16, n4 = (tid & 15) * 4;
        const float4 v = *(const float4*)(W + (size_t)(k0 + k) * 1024 + n0 + n4);
        T[k][n4] = v.x; T[k][n4+1] = v.y; T[k][n4+2] = v.z; T[k][n4+3] = v.w;
    }
    __syncthreads();
    if (z == 3) {
        #pragma unroll
        for (int i = 0; i < 4; i++) {
            const int n = (tid >> 4) + i * 16, k4 = (tid & 15) * 4;
            unsigned short u[4];
            #pragma unroll
            for (int j = 0; j < 4; j++) {
                const int q = k4 + j;                      // Ab storage pos
                const int p = (q & 3) * 16 + (q >> 2);     // inv sigma
                const int d = (p & 3) * 16 + (p >> 2);     // inv pi
                u[j] = f2bf(T[d][n]);
            }
            *(int2*)(O + (size_t)(n0 + n) * 1024 + k0 + k4) = *(int2*)u;
        }
    } else {
        #pragma unroll
        for (int i = 0; i < 4; i++) {
            const int n = (tid >> 4) + i * 16, k4 = (tid & 15) * 4;
            unsigned short u[4] = { f2bf(T[k4][n]), f2bf(T[k4+1][n]),
                                    f2bf(T[k4+2][n]), f2bf(T[k4+3][n]) };
            *(int2*)(O + (size_t)(n0 + n) * 1024 + k0 + k4) = *(int2*)u;
        }
    }
}

// ---------------------------------------------------------------------------
// QKV GEMM, R16 (= R15 resubmit after infra failure; race + swizzle audited):
// 128x128 tile (R13 geometry, grid (32,8,3)) with two per-K-step serial
// costs removed:
//  (1) 2-phase double-buffered staging: STAGE(t+1) issued BEFORE compute(t);
//      ONE __syncthreads()/step (implicit vmcnt(0) drains the prefetch) ->
//      barriers halve, GLDS latency hides under ds_read+MFMA.
//  (2) XOR slot-swizzle (both-sides): GLDS dest linear; global SOURCE slot
//      pre-swizzled (lane&3 ^ (lane>>3)&3); reads XOR the same involution
//      (quad ^ (c>>1)&3) -> per-quad b128 reads cover all 8 bank positions
//      (was 2) -> 8-way conflict becomes 2-way (free, m136).
// ---------------------------------------------------------------------------
__global__ __launch_bounds__(256)
void qkv_gemm(const unsigned short* __restrict__ Xb,
              const unsigned short* __restrict__ Wtq, const unsigned short* __restrict__ Wtk,
              const unsigned short* __restrict__ Wtv,
              const float* __restrict__ bq, const float* __restrict__ bk,
              const float* __restrict__ bv,
              unsigned short* __restrict__ Qb, unsigned short* __restrict__ Kb,
              unsigned short* __restrict__ Vtb)
{
    const unsigned short* Wt; const float* bias; unsigned short* Out;
    const int z = blockIdx.z;
    if (z == 0)      { Wt = Wtq; bias = bq; Out = Qb; }
    else if (z == 1) { Wt = Wtk; bias = bk; Out = Kb; }
    else             { Wt = Wtv; bias = bv; Out = Vtb; }

    __shared__ unsigned short Sh[16384];             // 32KB: 2x(As 4K + Bs 4K)
    unsigned short* T = Sh;                          // 128*72 epilogue transpose

    const int tid = threadIdx.x, lane = tid & 63, w = tid >> 6;
    const int quad = lane >> 4, c = lane & 15;
    const int wr = w >> 1, wc = w & 1;
    const int m0 = blockIdx.x * 128, n0 = blockIdx.y * 128;
    const int srow = lane >> 2;
    const int scol = ((lane & 3) ^ ((lane >> 3) & 3)) * 8;   // pre-swizzled src slot
    const int sA = (quad ^ ((c >> 1) & 3)) * 8;              // swizzled read slot

    f32x4 acc[4][4];
    #pragma unroll
    for (int i = 0; i < 4; i++)
        #pragma unroll
        for (int j = 0; j < 4; j++) acc[i][j] = (f32x4){0.f, 0.f, 0.f, 0.f};

    // ---- prologue: stage tile 0 into buffer 0 ----
    #pragma unroll
    for (int j = 0; j < 2; j++) {
        const int r = w * 32 + j * 16;
        GLDS16(Xb + (size_t)(m0 + r + srow) * 1024 + 0 + scol, &Sh[r * 32]);
        GLDS16(Wt + (size_t)(n0 + r + srow) * 1024 + 0 + scol, &Sh[4096 + r * 32]);
    }
    __syncthreads();

    int cur = 0;
    for (int t = 0; t < 32; ++t) {
        // issue next-tile loads into the other buffer (overlap with compute)
        if (t + 1 < 32) {
            const int kn = (t + 1) * 32;
            unsigned short* An = Sh + (cur ^ 1) * 8192;
            unsigned short* Bn = An + 4096;
            #pragma unroll
            for (int j = 0; j < 2; j++) {
                const int r = w * 32 + j * 16;
                GLDS16(Xb + (size_t)(m0 + r + srow) * 1024 + kn + scol, &An[r * 32]);
                GLDS16(Wt + (size_t)(n0 + r + srow) * 1024 + kn + scol, &Bn[r * 32]);
            }
        }
        const unsigned short* As = Sh + cur * 8192;
        const unsigned short* Bs = As + 4096;
        bf16x8 af[4], bf[4];
        #pragma unroll
        for (int rt = 0; rt < 4; rt++)
            af[rt] = *(const bf16x8*)&As[(wr * 64 + rt * 16 + c) * 32 + sA];
        #pragma unroll
        for (int nt = 0; nt < 4; nt++)
            bf[nt] = *(const bf16x8*)&Bs[(wc * 64 + nt * 16 + c) * 32 + sA];
        #pragma unroll
        for (int rt = 0; rt < 4; rt++)
            #pragma unroll
            for (int nt = 0; nt < 4; nt++)
                acc[rt][nt] = __builtin_amdgcn_mfma_f32_16x16x32_bf16(af[rt], bf[nt], acc[rt][nt], 0, 0, 0);
        __syncthreads();   // drains vmcnt(0): next buffer ready; cur reads done
        cur ^= 1;
    }

    float bv4[4];
    #pragma unroll
    for (int nt = 0; nt < 4; nt++) bv4[nt] = bias[n0 + wc * 64 + nt * 16 + c];

    if (z == 2) {
        const int b = m0 >> 11, sb = m0 & 2047;
        const int hgbase = n0 >> 6;
        #pragma unroll
        for (int h = 0; h < 2; h++) {
            if (wc == h) {
                #pragma unroll
                for (int rt = 0; rt < 4; rt++)
                    #pragma unroll
                    for (int reg = 0; reg < 4; reg++) {
                        const int s = wr * 64 + rt * 16 + quad * 4 + reg;
                        unsigned short u[4];
                        #pragma unroll
                        for (int nt = 0; nt < 4; nt++)
                            u[nt] = f2bf(acc[rt][nt][reg] + bv4[nt]);
                        *(int2*)&T[s * 72 + c * 4] = *(int2*)u;   // p = c*4+nt (sigma)
                    }
            }
            __syncthreads();
            const int p = tid >> 2, s8 = (tid & 3) * 32;
            unsigned short* dstb = Vtb + ((size_t)(b * 16 + hgbase + h) * 64 + p) * 2048 + sb;
            #pragma unroll
            for (int jj = 0; jj < 32; jj += 8) {
                unsigned short u[8];
                #pragma unroll
                for (int j = 0; j < 8; j++) u[j] = T[(s8 + jj + j) * 72 + p];
                *(int4*)(dstb + s8 + jj) = *(int4*)u;
            }
            __syncthreads();
        }
        return;
    }

    const float kLn = 9.210340371976184f / 32.0f;   // ln(10000)/32
    const float TWO_PI_INV = 0.15915494309189535f;
    const float rv0 = expf(-(float)c * kLn) * TWO_PI_INV;
    const float rv1 = expf(-(float)(c + 16) * kLn) * TWO_PI_INV;
    const float qscale = (z == 0) ? 0.125f : 1.0f;  // fold 1/sqrt(64) into Q

    #pragma unroll
    for (int rt = 0; rt < 4; rt++) {
        #pragma unroll
        for (int reg = 0; reg < 4; reg++) {
            const int m = m0 + wr * 64 + rt * 16 + quad * 4 + reg;
            const int b = m >> 11, s = m & 2047;
            float x0 = acc[rt][0][reg] + bv4[0];
            float x1 = acc[rt][1][reg] + bv4[1];
            float x2 = acc[rt][2][reg] + bv4[2];
            float x3 = acc[rt][3][reg] + bv4[3];
            float r0 = (float)s * rv0;  r0 -= floorf(r0);
            float r1 = (float)s * rv1;  r1 -= floorf(r1);
            const float sn0 = __builtin_amdgcn_sinf(r0);
            const float cs0 = __builtin_amdgcn_cosf(r0);
            const float sn1 = __builtin_amdgcn_sinf(r1);
            const float cs1 = __builtin_amdgcn_cosf(r1);
            const float y0 = (x0 * cs0 - x2 * sn0) * qscale;
            const float y2 = (x0 * sn0 + x2 * cs0) * qscale;
            const float y1 = (x1 * cs1 - x3 * sn1) * qscale;
            const float y3 = (x1 * sn1 + x3 * cs1) * qscale;
            const int h = (n0 + wc * 64) >> 6;
            unsigned short u[4] = { f2bf(y0), f2bf(y1), f2bf(y2), f2bf(y3) };
            unsigned short* dst = Out + ((size_t)(b * 16 + h) * 2048 + s) * 64;
            *(int2*)(dst + c * 4) = *(int2*)u;     // pi: pos c*4+nt
        }
    }
}

// ---------------------------------------------------------------------------
// Output projection GEMM (unchanged): 64x128 tile, 512 blocks (2/CU).
// ---------------------------------------------------------------------------
__global__ __launch_bounds__(256)
void out_gemm(const unsigned short* __restrict__ Ab, const unsigned short* __restrict__ Wto,
              const float* __restrict__ bo, float* __restrict__ Out)
{
    __shared__ unsigned short As[64 * 32];
    __shared__ unsigned short Bs[128 * 32];
    const int tid = threadIdx.x, lane = tid & 63, w = tid >> 6;
    const int quad = lane >> 4, c = lane & 15;
    const int wr = w >> 1, wc = w & 1;
    const int m0 = blockIdx.x * 64, n0 = blockIdx.y * 128;
    const int srow = lane >> 2, scol = (lane & 3) * 8;

    f32x4 acc[2][4];
    #pragma unroll
    for (int i = 0; i < 2; i++)
        #pragma unroll
        for (int j = 0; j < 4; j++) acc[i][j] = (f32x4){0.f, 0.f, 0.f, 0.f};

    for (int k0 = 0; k0 < 1024; k0 += 32) {
        {
            const int r = w * 16;
            GLDS16(Ab + (size_t)(m0 + r + srow) * 1024 + k0 + scol, &As[r * 32]);
        }
        #pragma unroll
        for (int j = 0; j < 2; j++) {
            const int r = w * 32 + j * 16;
            GLDS16(Wto + (size_t)(n0 + r + srow) * 1024 + k0 + scol, &Bs[r * 32]);
        }
        __syncthreads();
        bf16x8 af[2], bf[4];
        #pragma unroll
        for (int rt = 0; rt < 2; rt++)
            af[rt] = *(const bf16x8*)&As[(wr * 32 + rt * 16 + c) * 32 + quad * 8];
        #pragma unroll
        for (int nt = 0; nt < 4; nt++)
            bf[nt] = *(const bf16x8*)&Bs[(wc * 64 + nt * 16 + c) * 32 + quad * 8];
        #pragma unroll
        for (int rt = 0; rt < 2; rt++)
            #pragma unroll
            for (int nt = 0; nt < 4; nt++)
                acc[rt][nt] = __builtin_amdgcn_mfma_f32_16x16x32_bf16(af[rt], bf[nt], acc[rt][nt], 0, 0, 0);
        __syncthreads();
    }
    #pragma unroll
    for (int rt = 0; rt < 2; rt++) {
        #pragma unroll
        for (int reg = 0; reg < 4; reg++) {
            const int m = m0 + wr * 32 + rt * 16 + quad * 4 + reg;
            #pragma unroll
            for (int nt = 0; nt < 4; nt++) {
                const int n = n0 + wc * 64 + nt * 16 + c;
                Out[(size_t)m * 1024 + n] = acc[rt][nt][reg] + bo[n];
            }
        }
    }
}

// ---------------------------------------------------------------------------
// Split-K flash attention (unchanged from R13): 512 threads, 8 waves,
// 32 q/wave via 2 Q-fragments, P fully in-register (kappa relabel).
// ---------------------------------------------------------------------------
__global__ __launch_bounds__(512)
void attn_part(const unsigned short* __restrict__ Qb, const unsigned short* __restrict__ Kb,
               const unsigned short* __restrict__ Vtb, unsigned short* __restrict__ Ab,
               float* __restrict__ Opart, float* __restrict__ Lpart)
{
    __shared__ unsigned short Ks[64 * 72];      // [key][d], pitch 144B
    __shared__ unsigned short Vs[64 * 72];      // [p][key], pitch 144B

    const int tid = threadIdx.x, w = tid >> 6, lane = tid & 63;
    const int quad = lane >> 4, c = lane & 15;
    const int bh = blockIdx.y;
    const int x = blockIdx.x;
    // i per x: {7,7,3,6,6,5,5,2,4,4,1,0}; chunk1 at x in {1,4,6,9}
    const int i = (int)((0x014425566377ULL >> (4 * x)) & 15);
    const int chunk = (594 >> x) & 1;                   // bits 1,4,6,9
    const int len = ((i >= 4) ? 2 : 4) * (i + 1);
    const int start = chunk ? len : 0;
    const int q0 = i * 256;
    const bool complete = (i <= 3);
    const size_t base = (size_t)bh * 2048 * 64;

    bf16x8 on;                                  // bf16 1.0 x8 (ones column)
    #pragma unroll
    for (int ii = 0; ii < 8; ii++) on[ii] = (short)0x3F80;

    const int qbase = q0 + w * 32;              // wave owns rows [qbase, qbase+32)
    const size_t qoffA = base + (size_t)(qbase + c) * 64;
    const size_t qoffB = base + (size_t)(qbase + 16 + c) * 64;
    const bf16x8 qfA0 = *(const bf16x8*)(Qb + qoffA + quad * 8);
    const bf16x8 qfA1 = *(const bf16x8*)(Qb + qoffA + 32 + quad * 8);
    const bf16x8 qfB0 = *(const bf16x8*)(Qb + qoffB + quad * 8);
    const bf16x8 qfB1 = *(const bf16x8*)(Qb + qoffB + 32 + quad * 8);

    f32x4 OA[4], OB[4], OsA, OsB;
    OsA = (f32x4){0.f, 0.f, 0.f, 0.f};
    OsB = (f32x4){0.f, 0.f, 0.f, 0.f};
    #pragma unroll
    for (int nt = 0; nt < 4; nt++) { OA[nt] = OsA; OB[nt] = OsA; }

    // staging: 512 threads cover 64 rows x 64 elems (16B each) in one shot
    const int rs = tid >> 3, c8 = (tid & 7) * 8;

    int k0 = start * 64;
    int4 kreg = *(const int4*)(Kb  + base + (size_t)(k0 + rs) * 64 + c8);
    int4 vreg = *(const int4*)(Vtb + base + (size_t)rs * 2048 + k0 + c8);

    union P8 { bf16x8 v8; unsigned wd[4]; };
    union V8 { bf16x8 v8; bf16x4 v4[2]; };

    for (int t = 0; t < len; t++, k0 += 64) {
        *(int4*)&Ks[(size_t)rs * 72 + c8] = kreg;
        *(int4*)&Vs[(size_t)rs * 72 + c8] = vreg;
        __syncthreads();

        if (t + 1 < len) {
            const int kn = k0 + 64;
            kreg = *(const int4*)(Kb  + base + (size_t)(kn + rs) * 64 + c8);
            vreg = *(const int4*)(Vtb + base + (size_t)rs * 2048 + kn + c8);
        }

        if (k0 <= qbase + 31) {                 // wave-uniform: else fully masked
            const int qrowA = qbase + c;
            const int qrowB = qbase + 16 + c;
            const bool nmA = (k0 + 63) > qbase;
            const bool nmB = (k0 + 63) > (qbase + 16);
            P8 paA0, paA1, paB0, paB1;
            __builtin_amdgcn_s_setprio(1);
            #pragma unroll
            for (int nt = 0; nt < 4; nt++) {
                const bf16x8 kf0 = *(const bf16x8*)&Ks[(nt * 16 + c) * 72 + quad * 8];
                const bf16x8 kf1 = *(const bf16x8*)&Ks[(nt * 16 + c) * 72 + 32 + quad * 8];
                f32x4 sA = (f32x4){0.f, 0.f, 0.f, 0.f};
                f32x4 sB = sA;
                sA = __builtin_amdgcn_mfma_f32_16x16x32_bf16(kf0, qfA0, sA, 0, 0, 0);
                sA = __builtin_amdgcn_mfma_f32_16x16x32_bf16(kf1, qfA1, sA, 0, 0, 0);
                sB = __builtin_amdgcn_mfma_f32_16x16x32_bf16(kf0, qfB0, sB, 0, 0, 0);
                sB = __builtin_amdgcn_mfma_f32_16x16x32_bf16(kf1, qfB1, sB, 0, 0, 0);
                const int keyb = k0 + nt * 16 + quad * 4;
                float pA[4], pB[4];
                #pragma unroll
                for (int reg = 0; reg < 4; reg++) {
                    float va = __expf(sA[reg]);           // Q pre-scaled by 0.125
                    if (nmA && (keyb + reg > qrowA)) va = 0.f;
                    pA[reg] = va;
                    float vb = __expf(sB[reg]);
                    if (nmB && (keyb + reg > qrowB)) vb = 0.f;
                    pB[reg] = vb;
                }
                const unsigned waA = cvt_pk_bf16(pA[0], pA[1]);
                const unsigned wbA = cvt_pk_bf16(pA[2], pA[3]);
                const unsigned waB = cvt_pk_bf16(pB[0], pB[1]);
                const unsigned wbB = cvt_pk_bf16(pB[2], pB[3]);
                // kappa mapping: frag (nt>>1), words 2*(nt&1)+{0,1}
                if (nt < 2) {
                    paA0.wd[2 * nt] = waA;     paA0.wd[2 * nt + 1] = wbA;
                    paB0.wd[2 * nt] = waB;     paB0.wd[2 * nt + 1] = wbB;
                } else {
                    paA1.wd[2 * (nt-2)] = waA; paA1.wd[2 * (nt-2) + 1] = wbA;
                    paB1.wd[2 * (nt-2)] = waB; paB1.wd[2 * (nt-2) + 1] = wbB;
                }
            }

            // ---- PV + row-sum; vb reads shared by both fragments ----
            #pragma unroll
            for (int nt = 0; nt < 4; nt++) {
                const int pr = (nt * 16 + c) * 72 + 4 * quad;
                V8 vb0, vb1;
                vb0.v4[0] = *(const bf16x4*)&Vs[pr];
                vb0.v4[1] = *(const bf16x4*)&Vs[pr + 16];
                vb1.v4[0] = *(const bf16x4*)&Vs[pr + 32];
                vb1.v4[1] = *(const bf16x4*)&Vs[pr + 48];
                OA[nt] = __builtin_amdgcn_mfma_f32_16x16x32_bf16(paA0.v8, vb0.v8, OA[nt], 0, 0, 0);
                OA[nt] = __builtin_amdgcn_mfma_f32_16x16x32_bf16(paA1.v8, vb1.v8, OA[nt], 0, 0, 0);
                OB[nt] = __builtin_amdgcn_mfma_f32_16x16x32_bf16(paB0.v8, vb0.v8, OB[nt], 0, 0, 0);
                OB[nt] = __builtin_amdgcn_mfma_f32_16x16x32_bf16(paB1.v8, vb1.v8, OB[nt], 0, 0, 0);
            }
            OsA = __builtin_amdgcn_mfma_f32_16x16x32_bf16(paA0.v8, on, OsA, 0, 0, 0);
            OsA = __builtin_amdgcn_mfma_f32_16x16x32_bf16(paA1.v8, on, OsA, 0, 0, 0);
            OsB = __builtin_amdgcn_mfma_f32_16x16x32_bf16(paB0.v8, on, OsB, 0, 0, 0);
            OsB = __builtin_amdgcn_mfma_f32_16x16x32_bf16(paB1.v8, on, OsB, 0, 0, 0);
            __builtin_amdgcn_s_setprio(0);
        }
        __syncthreads();
    }

    if (complete) {
        const int b = bh >> 4, h = bh & 15;
        #pragma unroll
        for (int reg = 0; reg < 4; reg++) {
            const float invA = 1.0f / OsA[reg];
            const int qA = qbase + quad * 4 + reg;
            unsigned short uA[4];
            #pragma unroll
            for (int nt = 0; nt < 4; nt++) uA[nt] = f2bf(OA[nt][reg] * invA);
            unsigned short* dA = Ab + ((size_t)(b * 2048 + qA)) * 1024 + h * 64;
            *(int2*)(dA + c * 4) = *(int2*)uA;     // sigma: pos c*4+nt

            const float invB = 1.0f / OsB[reg];
            const int qB = qbase + 16 + quad * 4 + reg;
            unsigned short uB[4];
            #pragma unroll
            for (int nt = 0; nt < 4; nt++) uB[nt] = f2bf(OB[nt][reg] * invB);
            unsigned short* dB = Ab + ((size_t)(b * 2048 + qB)) * 1024 + h * 64;
            *(int2*)(dB + c * 4) = *(int2*)uB;
        }
    } else {
        const int slot = (i - 4) * 2 + chunk;               // [0,8)
        float* Op = Opart + ((size_t)bh * 8 + slot) * 16384;
        float* Lp = Lpart + (size_t)bh * 2048 + (size_t)slot * 256;
        #pragma unroll
        for (int reg = 0; reg < 4; reg++) {
            const int rowA = w * 32 + quad * 4 + reg;       // [0,256)
            float4 oA = make_float4(OA[0][reg], OA[1][reg], OA[2][reg], OA[3][reg]);
            *(float4*)(Op + (size_t)rowA * 64 + c * 4) = oA;  // sigma order
            if (c == 0) Lp[rowA] = OsA[reg];

            const int rowB = rowA + 16;
            float4 oB = make_float4(OB[0][reg], OB[1][reg], OB[2][reg], OB[3][reg]);
            *(float4*)(Op + (size_t)rowB * 64 + c * 4) = oB;
            if (c == 0) Lp[rowB] = OsB[reg];
        }
    }
}

// ---------------------------------------------------------------------------
// Combine two partials per (bh, q-tile256 i=4..7): O=O0+O1, normalize, bf16.
// grid (8,32): j -> (i = 4 + j/2, half = j&1) covering 128 rows each.
// ---------------------------------------------------------------------------
__global__ __launch_bounds__(256)
void attn_combine(const float* __restrict__ Opart, const float* __restrict__ Lpart,
                  unsigned short* __restrict__ Ab)
{
    const int tid = threadIdx.x;
    const int j = blockIdx.x, bh = blockIdx.y;
    const int i = 4 + (j >> 1), half = j & 1;
    const int slot0 = (i - 4) * 2;
    const int q0 = i * 256 + half * 128;
    const size_t s0 = ((size_t)bh * 8 + slot0) * 16384 + (size_t)half * 128 * 64;
    const size_t l0 = (size_t)bh * 2048 + (size_t)slot0 * 256 + half * 128;

    __shared__ float linv[128];
    if (tid < 128) linv[tid] = 1.0f / (Lpart[l0 + tid] + Lpart[l0 + 256 + tid]);
    __syncthreads();

    const int row = tid >> 1, col0 = (tid & 1) * 32;
    const float inv = linv[row];
    const int b = bh >> 4, h = bh & 15;
    const int q = q0 + row;
    unsigned short* dst = Ab + ((size_t)(b * 2048 + q)) * 1024 + h * 64 + col0;
    #pragma unroll
    for (int c4 = 0; c4 < 32; c4 += 4) {
        const float4 a  = *(const float4*)(Opart + s0 + (size_t)row * 64 + col0 + c4);
        const float4 bb = *(const float4*)(Opart + s0 + 16384 + (size_t)row * 64 + col0 + c4);
        dst[c4 + 0] = f2bf((a.x + bb.x) * inv);
        dst[c4 + 1] = f2bf((a.y + bb.y) * inv);
        dst[c4 + 2] = f2bf((a.z + bb.z) * inv);
        dst[c4 + 3] = f2bf((a.w + bb.w) * inv);
    }
}

// ---------------------------------------------------------------------------
extern "C" void kernel_launch(void* const* d_in, const int* in_sizes, int n_in,
                              void* d_out, int out_size, void* d_ws, size_t ws_size,
                              hipStream_t stream)
{
    const float* X  = (const float*)d_in[0];
    const float* wq = (const float*)d_in[2];
    const float* bq = (const float*)d_in[3];
    const float* wk = (const float*)d_in[4];
    const float* bk = (const float*)d_in[5];
    const float* wv = (const float*)d_in[6];
    const float* bv = (const float*)d_in[7];
    const float* wo = (const float*)d_in[8];
    const float* bo = (const float*)d_in[9];

    unsigned short* ws = (unsigned short*)d_ws;
    const size_t M1 = 1024 * 1024;
    unsigned short* Xb  = ws;             // 4M elems
    unsigned short* Wtq = Xb  + 4 * M1;   // 1M each
    unsigned short* Wtk = Wtq + M1;
    unsigned short* Wtv = Wtk + M1;
    unsigned short* Wto = Wtv + M1;
    unsigned short* Qb  = Wto + M1;       // 4M each
    unsigned short* Kb  = Qb  + 4 * M1;
    unsigned short* Vtb = Kb  + 4 * M1;   // V^T written directly by qkv_gemm
    unsigned short* Ab  = Vtb + 4 * M1;   // bf16, 4M elems
    float* Opart = (float*)(Ab + 4 * M1); // 32*8*16384 fp32 = 16 MB
    float* Lpart = Opart + (size_t)32 * 8 * 16384;  // 64K fp32

    prep        <<<dim3(16, 16, 12), 256, 0, stream>>>(X, Xb, wq, wk, wv, wo,
                                                       Wtq, Wtk, Wtv, Wto);
    qkv_gemm    <<<dim3(32, 8, 3), 256, 0, stream>>>(Xb, Wtq, Wtk, Wtv, bq, bk, bv,
                                                     Qb, Kb, Vtb);
    attn_part   <<<dim3(12, 32), 512, 0, stream>>>(Qb, Kb, Vtb, Ab, Opart, Lpart);
    attn_combine<<<dim3(8, 32), 256, 0, stream>>>(Opart, Lpart, Ab);
    out_gemm    <<<dim3(64, 8), 256, 0, stream>>>(Ab, Wto, bo, (float*)d_out);
}